// Round 19
// baseline (45.417 us; speedup 1.0000x reference)
//
#include <hip/hip_runtime.h>

#define N_ 8
#define C_ 64
#define P_ 4096

typedef float f32x4 __attribute__((ext_vector_type(4)));
typedef float f32x2 __attribute__((ext_vector_type(2)));
typedef short bf16x8 __attribute__((ext_vector_type(8)));
typedef unsigned long long u64;

__device__ __forceinline__ unsigned short f2bf(float f) {
  unsigned int u = __builtin_bit_cast(unsigned int, f);
  u = (u + 0x7fffu + ((u >> 16) & 1u)) >> 16;  // RNE
  return (unsigned short)u;
}

// Schraudolph fast 2^x (FMA pipe). pos/tot share the approx -> ratio error
// cancels; loss error ~1e-2 vs threshold 0.166.
__device__ __forceinline__ float exp2appr(float x) {
  const int i = (int)__builtin_fmaf(x, 8388608.0f, 1064992209.0f);
  return __builtin_bit_cast(float, i);
}

// Kernel 1: L2-normalize along C, write bf16 transposed to [N][P][C].
// Split-C (2 threads per p). rgb pre-scaled by 10*log2(e); ir rows
// 16B-group XOR-swizzled (g ^= p&7) matching the gemm's fragment offsets.
__global__ void __launch_bounds__(256) norm_transpose(
    const float* __restrict__ rgb, const float* __restrict__ ir,
    unsigned short* __restrict__ rgbnT, unsigned short* __restrict__ irnT) {
  const int tid = threadIdx.x;
  const int half = tid >> 7;
  const int pl = tid & 127;
  const int gp = blockIdx.x * 128 + pl;
  const int n = gp >> 12;
  const int p = gp & (P_ - 1);
  const float* src = (blockIdx.y == 0) ? rgb : ir;
  unsigned short* dst = (blockIdx.y == 0) ? rgbnT : irnT;
  const float SC = 14.4269504088896340736f;  // 10*log2(e)
  const float* col = src + (size_t)n * C_ * P_ + (size_t)(half * 32) * P_ + p;
  float v[32];
  float ss = 0.f;
#pragma unroll
  for (int c = 0; c < 32; ++c) {
    v[c] = col[(size_t)c * P_];
    ss += v[c] * v[c];
  }
  __shared__ float ssq[2][128];
  ssq[half][pl] = ss;
  __syncthreads();
  const float tot = ssq[0][pl] + ssq[1][pl];
  float inv = 1.0f / fmaxf(sqrtf(tot), 1e-12f);
  if (blockIdx.y == 0) inv *= SC;
  const int gx = (blockIdx.y == 0) ? 0 : (p & 7);
  unsigned short* o = dst + (size_t)gp * C_;
#pragma unroll
  for (int gi = 0; gi < 4; ++gi) {
    bf16x8 pack;
#pragma unroll
    for (int j = 0; j < 8; ++j) pack[j] = (short)f2bf(v[gi * 8 + j] * inv);
    const int gg = half * 4 + gi;
    *reinterpret_cast<bf16x8*>(o + (gg ^ gx) * 8) = pack;
  }
}

// Kernel 2: 256p x 512q, 4 INDEPENDENT waves x 64 p-rows. NO LDS, NO
// barriers, NO global_load_lds: B fragments load DIRECTLY to a 2-deep
// register ring via inline-asm global_load_dwordx4 (asm loads cannot be
// sunk -- R3's reg-staged failure -- and asm-produced values carry no
// compiler waitcnt obligation -- R14's mechanism -- so the only waits are
// our counted vmcnt(8)). global_load_lds was the one mechanism common to
// all six ~40us-invariant variants (R10..R18); this removes it.
// vmcnt accounting (ALL loads are asm): prologue af(8)+t0(8)+t1(8)=24
// outstanding; each iter waits vmcnt(8) (drains af+t0 first time, then
// tile t), computes ring[t&1], then issues 8 loads for t+2 into the slot
// just consumed (uniform count; tail loads land in dead slots, addresses
// stay inside d_ws).
__global__ void __launch_bounds__(256) gemm_exp_reduce(
    const unsigned short* __restrict__ aT, const unsigned short* __restrict__ bT,
    float* __restrict__ partials) {
  const int lin = blockIdx.x;
  const int n = lin & 7;
  const int local = lin >> 3;
  const int pc = local & 15;  // 16 p-chunks of 256
  const int qc = local >> 4;  // 8 q-chunks of 512
  const int tid = threadIdx.x;
  const int lane = tid & 63;
  const int wid = tid >> 6;
  const int pbase = pc * 256 + wid * 64;
  const int q0 = qc * 512;
  const unsigned short* A = aT + (size_t)n * P_ * C_;
  const unsigned short* B = bT + (size_t)n * P_ * C_;
  const int r16 = lane & 15;
  const int kofs = (lane >> 4) * 8;

  // B-fragment per-lane addresses for tile 0 (row-swizzled layout; 16B
  // aligned), advanced by 8192 B per tile.
  u64 ba[8];
#pragma unroll
  for (int ks = 0; ks < 2; ++ks)
#pragma unroll
    for (int ni = 0; ni < 4; ++ni) {
      const int row = ni * 16 + r16;
      const int seg = ks * 4 + (lane >> 4);
      const int fo = row * 128 + ((seg ^ (lane & 7)) * 16);
      ba[ks * 4 + ni] = (u64)(size_t)B + (u64)(q0 * 128 + fo);
    }

  // A fragments via asm loads (so compiler tracks zero vmem ops).
  f32x4 af[2][4];
#pragma unroll
  for (int ks = 0; ks < 2; ++ks)
#pragma unroll
    for (int mi = 0; mi < 4; ++mi) {
      const u64 aa = (u64)(size_t)(A + (size_t)(pbase + mi * 16 + r16) * C_ +
                                   ks * 32 + kofs);
      asm volatile("global_load_dwordx4 %0, %1, off"
                   : "=v"(af[ks][mi]) : "v"(aa));
    }

  // Prologue: tiles 0 and 1 into the register ring.
  f32x4 br0[2][4], br1[2][4];
#pragma unroll
  for (int j = 0; j < 8; ++j)
    asm volatile("global_load_dwordx4 %0, %1, off"
                 : "=v"(br0[j >> 2][j & 3]) : "v"(ba[j]));
#pragma unroll
  for (int j = 0; j < 8; ++j)
    asm volatile("global_load_dwordx4 %0, %1, off"
                 : "=v"(br1[j >> 2][j & 3]) : "v"(ba[j] + 8192));
#pragma unroll
  for (int j = 0; j < 8; ++j) ba[j] += 16384;  // -> tile 2

  const f32x4 zc = (f32x4)(0.f);
  f32x2 ch2[8];
#pragma unroll
  for (int k = 0; k < 8; ++k) ch2[k] = (f32x2)(0.f);
  float pos = 0.f;
  const int col = lane & 15;
  const int rowb = (lane >> 4) * 4;

#pragma unroll 2
  for (int t = 0; t < 8; ++t) {
    // Drain down to 8 outstanding: tile t (and af on the first pass)
    // landed; tile t+1's 8 loads stay in flight.
    asm volatile("s_waitcnt vmcnt(8)" ::: "memory");
    __builtin_amdgcn_sched_barrier(0);

    f32x4(&br)[2][4] = (t & 1) ? br1 : br0;  // static after unroll 2

    f32x4 acc[4][4];
    __builtin_amdgcn_s_setprio(1);
#pragma unroll
    for (int mi = 0; mi < 4; ++mi)
#pragma unroll
      for (int ni = 0; ni < 4; ++ni)
        acc[mi][ni] = __builtin_amdgcn_mfma_f32_16x16x32_bf16(
            __builtin_bit_cast(bf16x8, af[0][mi]),
            __builtin_bit_cast(bf16x8, br[0][ni]), zc, 0, 0, 0);
#pragma unroll
    for (int mi = 0; mi < 4; ++mi)
#pragma unroll
      for (int ni = 0; ni < 4; ++ni)
        acc[mi][ni] = __builtin_amdgcn_mfma_f32_16x16x32_bf16(
            __builtin_bit_cast(bf16x8, af[1][mi]),
            __builtin_bit_cast(bf16x8, br[1][ni]), acc[mi][ni], 0, 0, 0);
    __builtin_amdgcn_s_setprio(0);

    // Epilogue: packed Schraudolph exp2 into 16 chains (8 f32x2).
#pragma unroll
    for (int mi = 0; mi < 4; ++mi)
#pragma unroll
      for (int ni = 0; ni < 4; ++ni) {
        const int base = ((mi * 4 + ni) & 3) * 2;
        const f32x4 v = acc[mi][ni];
        f32x2 a0, a1;
        a0[0] = v[0]; a0[1] = v[1];
        a1[0] = v[2]; a1[1] = v[3];
        const f32x2 f0 = a0 * 8388608.0f + (f32x2)(1064992209.0f);
        const f32x2 f1 = a1 * 8388608.0f + (f32x2)(1064992209.0f);
        f32x2 e0, e1;
        e0[0] = __builtin_bit_cast(float, (int)f0[0]);
        e0[1] = __builtin_bit_cast(float, (int)f0[1]);
        e1[0] = __builtin_bit_cast(float, (int)f1[0]);
        e1[1] = __builtin_bit_cast(float, (int)f1[1]);
        ch2[base] += e0;
        ch2[base + 1] += e1;
      }
    const int qb = q0 + t * 64;
    if (pbase == qb) {  // diagonal subtile
#pragma unroll
      for (int mi = 0; mi < 4; ++mi)
#pragma unroll
        for (int r = 0; r < 4; ++r)
          if (rowb + r == col) pos += exp2appr(acc[mi][mi][r]);
    }

    __builtin_amdgcn_sched_barrier(0);
    // Refill the just-consumed ring slot with tile t+2 (always 8 loads to
    // keep the vmcnt invariant; t>=6 issues land in dead slots).
#pragma unroll
    for (int j = 0; j < 8; ++j)
      asm volatile("global_load_dwordx4 %0, %1, off"
                   : "=v"(br[j >> 2][j & 3]) : "v"(ba[j]));
#pragma unroll
    for (int j = 0; j < 8; ++j) ba[j] += 8192;
  }

  f32x2 sum2 = ((ch2[0] + ch2[1]) + (ch2[2] + ch2[3])) +
               ((ch2[4] + ch2[5]) + (ch2[6] + ch2[7]));
  float tot = sum2[0] + sum2[1];
#pragma unroll
  for (int off = 32; off > 0; off >>= 1) {
    tot += __shfl_down(tot, off);
    pos += __shfl_down(pos, off);
  }
  __shared__ float sb[8];
  if (lane == 0) { sb[wid * 2] = pos; sb[wid * 2 + 1] = tot; }
  __syncthreads();
  if (tid == 0) {
    const float pp = sb[0] + sb[2] + sb[4] + sb[6];
    const float tt = sb[1] + sb[3] + sb[5] + sb[7];
    const int bid = n * 128 + pc * 8 + qc;
    partials[bid * 2] = pp;
    partials[bid * 2 + 1] = tt;
  }
}

// Kernel 3: reduce 128 partial pairs per n, compute loss. One pass.
__global__ void __launch_bounds__(1024) finalize(
    const float* __restrict__ partials, float* __restrict__ out) {
  const int tid = threadIdx.x;
  const int lane = tid & 63, wid = tid >> 6;
  __shared__ float sp[16], st[16], sl[8];
  const int n = tid >> 7;
  const int i = tid & 127;
  float p = partials[(n * 128 + i) * 2];
  float t = partials[(n * 128 + i) * 2 + 1];
#pragma unroll
  for (int off = 32; off > 0; off >>= 1) {
    p += __shfl_down(p, off);
    t += __shfl_down(t, off);
  }
  if (lane == 0) { sp[wid] = p; st[wid] = t; }
  __syncthreads();
  if (tid < 8) {
    const float pp = sp[2 * tid] + sp[2 * tid + 1];
    const float tt = st[2 * tid] + st[2 * tid + 1];
    sl[tid] = -logf(pp / (tt + 1e-6f));
  }
  __syncthreads();
  if (tid == 0) {
    float loss = 0.f;
#pragma unroll
    for (int k = 0; k < 8; ++k) loss += sl[k];
    out[0] = loss * (1.0f / N_);
  }
}

extern "C" void kernel_launch(void* const* d_in, const int* in_sizes, int n_in,
                              void* d_out, int out_size, void* d_ws, size_t ws_size,
                              hipStream_t stream) {
  const float* rgb = (const float*)d_in[0];
  const float* ir = (const float*)d_in[1];
  float* out = (float*)d_out;

  unsigned short* rgbnT = (unsigned short*)d_ws;              // 4 MB
  unsigned short* irnT = rgbnT + (size_t)N_ * P_ * C_;        // 4 MB
  float* partials = (float*)(irnT + (size_t)N_ * P_ * C_);    // 8 KB

  dim3 g1(N_ * P_ / 128, 2);
  norm_transpose<<<g1, 256, 0, stream>>>(rgb, ir, rgbnT, irnT);

  gemm_exp_reduce<<<1024, 256, 0, stream>>>(rgbnT, irnT, partials);

  finalize<<<1, 1024, 0, stream>>>(partials, out);
}